// Round 1
// 202.089 us; speedup vs baseline: 1.0437x; 1.0437x over previous
//
#include <hip/hip_runtime.h>
#include <cstdint>
#include <cstddef>

// DigitCapsule dynamic routing, fp32, b-per-lane layout.
// x[256,1152,8], W[1152,10,16,8], out v[256,10,16].
// vsum trick: logits at round r = votes . (v0+...+v_{r-1}).
constexpr int Bn = 256, In = 1152, Pn = 8, Jn = 10, Dn = 16;
constexpr int CA = 12, NCH = In / CA;  // capsA i-chunk, 96 chunks

// One-time transpose x[B][I*P] -> xT[I*P][B] so lane=b reads coalesce.
__global__ __launch_bounds__(256) void xpose(const float* __restrict__ x,
                                             float* __restrict__ xT) {
  __shared__ float tile[64][65];
  const int t = threadIdx.x, r = t >> 6, c = t & 63;
  const int ip0 = blockIdx.x * 64, b0 = blockIdx.y * 64;
  #pragma unroll
  for (int k = 0; k < 16; ++k) {
    const int row = k * 4 + r;
    tile[row][c] = x[(size_t)(b0 + row) * (In * Pn) + ip0 + c];
  }
  __syncthreads();
  #pragma unroll
  for (int k = 0; k < 16; ++k) {
    const int row = k * 4 + r;
    xT[(size_t)(ip0 + row) * Bn + b0 + c] = tile[c][row];
  }
}

// capsA: partial s[b,j,d] over an i-chunk. thread=b, block=(chunk, j).
// W addresses are wave-uniform -> SMEM; x/c loads coalesced b32.
// MODE 0: c = 0.1 ; MODE 1: c from cbuf[j][i][b].
template <int MODE>
__global__ __launch_bounds__(256) void capsA(
    const float* __restrict__ xT, const float* __restrict__ w,
    const float* __restrict__ cbuf, float* __restrict__ spart) {
  const int b = threadIdx.x, ch = blockIdx.x, j = blockIdx.y;
  float s[Dn];
  #pragma unroll
  for (int d = 0; d < Dn; ++d) s[d] = 0.f;

  const int i0 = ch * CA;
  for (int ii = 0; ii < CA; ++ii) {
    const int i = i0 + ii;
    const float* xr = xT + (size_t)i * (Pn * Bn) + b;
    float xc[Pn];
    #pragma unroll
    for (int p = 0; p < Pn; ++p) xc[p] = xr[p * Bn];
    float c = 0.1f;
    if (MODE) c = cbuf[((size_t)j * In + i) * Bn + b];
    #pragma unroll
    for (int p = 0; p < Pn; ++p) xc[p] *= c;

    const float* wr = w + ((size_t)i * Jn + j) * (Dn * Pn);
    #pragma unroll
    for (int d = 0; d < Dn; ++d) {
      const float* wd = wr + d * Pn;
      float dot = wd[0] * xc[0];
      dot = fmaf(wd[1], xc[1], dot); dot = fmaf(wd[2], xc[2], dot);
      dot = fmaf(wd[3], xc[3], dot); dot = fmaf(wd[4], xc[4], dot);
      dot = fmaf(wd[5], xc[5], dot); dot = fmaf(wd[6], xc[6], dot);
      dot = fmaf(wd[7], xc[7], dot);
      s[d] += dot;
    }
  }
  float* sp = spart + (((size_t)ch * Jn + j) * Dn) * Bn + b;
  #pragma unroll
  for (int d = 0; d < Dn; ++d) sp[d * Bn] = s[d];
}

// capsF v2: reduce 96 chunk-partials, squash.
// 1024 threads: thread = (d = t>>6, b-lane = t&63). Each thread privately
// accumulates ALL chunks for its (j,d,b) -> 640 waves (4x the old 160),
// deep MLP via pointer-bump + unroll, single LDS pass for the d-norm.
// MODE 0: vsumT = v ; MODE 1: vsumT += v ; MODE 2: out[b][j][d] = v.
template <int MODE>
__global__ __launch_bounds__(1024) void capsF(
    const float* __restrict__ spart, float* __restrict__ vsumT,
    float* __restrict__ out) {
  __shared__ float sred[Dn][64];
  __shared__ float ssc[64];
  const int t = threadIdx.x, bl = t & 63, d = t >> 6;
  const int j = blockIdx.x, b = blockIdx.y * 64 + bl;

  const size_t cstride = (size_t)Jn * Dn * Bn;  // chunk stride in floats
  const float* sp = spart + ((size_t)j * Dn + d) * Bn + b;
  float s0 = 0.f, s1 = 0.f;
  #pragma unroll 4
  for (int ch = 0; ch < NCH; ch += 2) {
    s0 += sp[0];
    s1 += sp[cstride];
    sp += 2 * cstride;
  }
  const float s = s0 + s1;
  sred[d][bl] = s;
  __syncthreads();
  if (t < 64) {
    float n2 = 0.f;
    #pragma unroll
    for (int dd = 0; dd < Dn; ++dd) {
      const float z = sred[dd][bl];
      n2 = fmaf(z, z, n2);
    }
    ssc[bl] = n2 / (1.f + n2) / sqrtf(n2 + 1e-7f);
  }
  __syncthreads();
  const float v = s * ssc[bl];
  if (MODE == 2) {
    out[((size_t)b * Jn + j) * Dn + d] = v;
  } else if (MODE == 1) {
    vsumT[((size_t)j * Dn + d) * Bn + b] += v;
  } else {
    vsumT[((size_t)j * Dn + d) * Bn + b] = v;
  }
}

// capsB: logits l[j] = sum_d vote(b,i,j,d)*vsum[b,j,d]; c = softmax_j -> cbuf[j][i][b].
// thread=b, block=i. No LDS; W wave-uniform (SMEM), vsumT/x/c coalesced.
__global__ __launch_bounds__(256) void capsB(
    const float* __restrict__ xT, const float* __restrict__ w,
    const float* __restrict__ vsumT, float* __restrict__ cbuf) {
  const int b = threadIdx.x, i = blockIdx.x;
  const float* xr = xT + (size_t)i * (Pn * Bn) + b;
  float xv[Pn];
  #pragma unroll
  for (int p = 0; p < Pn; ++p) xv[p] = xr[p * Bn];

  float l[Jn];
  #pragma unroll 2
  for (int j = 0; j < Jn; ++j) {
    const float* wr = w + ((size_t)i * Jn + j) * (Dn * Pn);
    float acc = 0.f;
    #pragma unroll
    for (int d = 0; d < Dn; ++d) {
      const float* wd = wr + d * Pn;
      float dot = wd[0] * xv[0];
      dot = fmaf(wd[1], xv[1], dot); dot = fmaf(wd[2], xv[2], dot);
      dot = fmaf(wd[3], xv[3], dot); dot = fmaf(wd[4], xv[4], dot);
      dot = fmaf(wd[5], xv[5], dot); dot = fmaf(wd[6], xv[6], dot);
      dot = fmaf(wd[7], xv[7], dot);
      acc = fmaf(dot, vsumT[((size_t)j * Dn + d) * Bn + b], acc);
    }
    l[j] = acc;
  }

  float m = l[0];
  #pragma unroll
  for (int j = 1; j < Jn; ++j) m = fmaxf(m, l[j]);
  float ssum = 0.f;
  #pragma unroll
  for (int j = 0; j < Jn; ++j) { l[j] = __expf(l[j] - m); ssum += l[j]; }
  const float inv = 1.f / ssum;
  #pragma unroll
  for (int j = 0; j < Jn; ++j)
    cbuf[((size_t)j * In + i) * Bn + b] = l[j] * inv;
}

extern "C" void kernel_launch(void* const* d_in, const int* in_sizes, int n_in,
                              void* d_out, int out_size, void* d_ws, size_t ws_size,
                              hipStream_t stream) {
  const float* x = (const float*)d_in[0];  // [256,1152,8]
  const float* w = (const float*)d_in[1];  // [1152,10,16,8]
  float* xT    = (float*)d_ws;                      // [I*P][B]   9.44 MB
  float* cbuf  = xT + (size_t)In * Pn * Bn;         // [J][I][B] 11.80 MB
  float* vsumT = cbuf + (size_t)Jn * In * Bn;       // [J][D][B]  0.16 MB
  float* spart = vsumT + (size_t)Jn * Dn * Bn;      // [NCH][J][D][B] 15.73 MB
  float* out = (float*)d_out;                       // [256,10,16]

  xpose<<<dim3((In * Pn) / 64, Bn / 64), 256, 0, stream>>>(x, xT);

  capsA<0><<<dim3(NCH, Jn), 256, 0, stream>>>(xT, w, nullptr, spart);
  capsF<0><<<dim3(Jn, 4), 1024, 0, stream>>>(spart, vsumT, out);   // vsum = v0

  capsB<<<In, 256, 0, stream>>>(xT, w, vsumT, cbuf);               // c1
  capsA<1><<<dim3(NCH, Jn), 256, 0, stream>>>(xT, w, cbuf, spart);
  capsF<1><<<dim3(Jn, 4), 1024, 0, stream>>>(spart, vsumT, out);   // vsum += v1

  capsB<<<In, 256, 0, stream>>>(xT, w, vsumT, cbuf);               // c2
  capsA<1><<<dim3(NCH, Jn), 256, 0, stream>>>(xT, w, cbuf, spart);
  capsF<2><<<dim3(Jn, 4), 1024, 0, stream>>>(spart, vsumT, out);   // out = v2
}

// Round 2
// 201.082 us; speedup vs baseline: 1.0489x; 1.0050x over previous
//
#include <hip/hip_runtime.h>
#include <cstdint>
#include <cstddef>

// DigitCapsule dynamic routing, fp32, b-per-lane layout.
// x[256,1152,8], W[1152,10,16,8], out v[256,10,16].
// vsum trick: logits at round r = votes . (v0+...+v_{r-1}).
// R1: fused round kernel capsR = capsB+capsA (votes computed ONCE per round,
// cbuf eliminated).
constexpr int Bn = 256, In = 1152, Pn = 8, Jn = 10, Dn = 16;
constexpr int CA = 12, NCH = In / CA;  // capsA/capsR i-chunk, 96 chunks

// One-time transpose x[B][I*P] -> xT[I*P][B] so lane=b reads coalesce.
__global__ __launch_bounds__(256) void xpose(const float* __restrict__ x,
                                             float* __restrict__ xT) {
  __shared__ float tile[64][65];
  const int t = threadIdx.x, r = t >> 6, c = t & 63;
  const int ip0 = blockIdx.x * 64, b0 = blockIdx.y * 64;
  #pragma unroll
  for (int k = 0; k < 16; ++k) {
    const int row = k * 4 + r;
    tile[row][c] = x[(size_t)(b0 + row) * (In * Pn) + ip0 + c];
  }
  __syncthreads();
  #pragma unroll
  for (int k = 0; k < 16; ++k) {
    const int row = k * 4 + r;
    xT[(size_t)(ip0 + row) * Bn + b0 + c] = tile[c][row];
  }
}

// capsA<0>: round-0 partial s[b,j,d] over an i-chunk with uniform c=0.1.
// thread=b, block=(chunk, j). W wave-uniform -> SMEM; x coalesced b32.
__global__ __launch_bounds__(256) void capsA0(
    const float* __restrict__ xT, const float* __restrict__ w,
    float* __restrict__ spart) {
  const int b = threadIdx.x, ch = blockIdx.x, j = blockIdx.y;
  float s[Dn];
  #pragma unroll
  for (int d = 0; d < Dn; ++d) s[d] = 0.f;

  const int i0 = ch * CA;
  for (int ii = 0; ii < CA; ++ii) {
    const int i = i0 + ii;
    const float* xr = xT + (size_t)i * (Pn * Bn) + b;
    float xc[Pn];
    #pragma unroll
    for (int p = 0; p < Pn; ++p) xc[p] = xr[p * Bn] * 0.1f;

    const float* wr = w + ((size_t)i * Jn + j) * (Dn * Pn);
    #pragma unroll
    for (int d = 0; d < Dn; ++d) {
      const float* wd = wr + d * Pn;
      float dot = wd[0] * xc[0];
      dot = fmaf(wd[1], xc[1], dot); dot = fmaf(wd[2], xc[2], dot);
      dot = fmaf(wd[3], xc[3], dot); dot = fmaf(wd[4], xc[4], dot);
      dot = fmaf(wd[5], xc[5], dot); dot = fmaf(wd[6], xc[6], dot);
      dot = fmaf(wd[7], xc[7], dot);
      s[d] += dot;
    }
  }
  float* sp = spart + (((size_t)ch * Jn + j) * Dn) * Bn + b;
  #pragma unroll
  for (int d = 0; d < Dn; ++d) sp[d * Bn] = s[d];
}

// capsR: fused routing round (replaces capsB + capsA<1>).
// 1024 threads: wave w = d (t>>6, 0..15), lane bl = t&63; b = blockIdx.y*64+bl.
// Per i: votes vt[j] for my d (once), logits partial vt*vs -> LDS, cross-wave
// reduce over d (2 barriers), softmax in-register, acc[j] += c*vt.
// Barrier hazard analysis: bar2 protects lds (stage-2 reads done before any
// next-iter stage-1 write); next-iter bar1 protects lsum (stage-3 reads done
// before any next-iter stage-2 write).
__global__ __launch_bounds__(1024) void capsR(
    const float* __restrict__ xT, const float* __restrict__ w,
    const float* __restrict__ vsumT, float* __restrict__ spart) {
  __shared__ float lds[Jn][Dn][64];   // 40 KB
  __shared__ float lsum[Jn][64];      // 2.5 KB
  const int t = threadIdx.x, bl = t & 63;
  const int d = __builtin_amdgcn_readfirstlane(t >> 6);  // wave-uniform
  const int ch = blockIdx.x, bg = blockIdx.y;
  const int b = bg * 64 + bl;

  float vs[Jn], acc[Jn];
  #pragma unroll
  for (int j = 0; j < Jn; ++j) {
    vs[j] = vsumT[((size_t)j * Dn + d) * Bn + b];
    acc[j] = 0.f;
  }

  const int i0 = ch * CA;
  for (int ii = 0; ii < CA; ++ii) {
    const int i = i0 + ii;
    const float* xr = xT + (size_t)i * (Pn * Bn) + b;
    float xc[Pn];
    #pragma unroll
    for (int p = 0; p < Pn; ++p) xc[p] = xr[p * Bn];

    float vt[Jn];
    #pragma unroll
    for (int j = 0; j < Jn; ++j) {
      const float* wd = w + (((size_t)i * Jn + j) * Dn + d) * Pn;
      float dot = wd[0] * xc[0];
      dot = fmaf(wd[1], xc[1], dot); dot = fmaf(wd[2], xc[2], dot);
      dot = fmaf(wd[3], xc[3], dot); dot = fmaf(wd[4], xc[4], dot);
      dot = fmaf(wd[5], xc[5], dot); dot = fmaf(wd[6], xc[6], dot);
      dot = fmaf(wd[7], xc[7], dot);
      vt[j] = dot;
      lds[j][d][bl] = dot * vs[j];
    }
    __syncthreads();  // bar1: all logit partials visible
    if (t < Jn * 64) {
      const int j2 = t >> 6, bl2 = t & 63;  // waves 0..9 each own a j
      float sum = 0.f;
      #pragma unroll
      for (int dd = 0; dd < Dn; ++dd) sum += lds[j2][dd][bl2];
      lsum[j2][bl2] = sum;
    }
    __syncthreads();  // bar2: lsum visible; lds free for next iter
    float l[Jn];
    #pragma unroll
    for (int j = 0; j < Jn; ++j) l[j] = lsum[j][bl];
    float m = l[0];
    #pragma unroll
    for (int j = 1; j < Jn; ++j) m = fmaxf(m, l[j]);
    float ssum = 0.f;
    #pragma unroll
    for (int j = 0; j < Jn; ++j) { l[j] = __expf(l[j] - m); ssum += l[j]; }
    const float inv = 1.f / ssum;
    #pragma unroll
    for (int j = 0; j < Jn; ++j) acc[j] = fmaf(l[j] * inv, vt[j], acc[j]);
  }

  #pragma unroll
  for (int j = 0; j < Jn; ++j)
    spart[(((size_t)ch * Jn + j) * Dn + d) * Bn + b] = acc[j];
}

// capsF: reduce 96 chunk-partials, squash.
// 1024 threads: thread = (d = t>>6, b-lane = t&63), private chunk loop.
// MODE 0: vsumT = v ; MODE 1: vsumT += v ; MODE 2: out[b][j][d] = v.
template <int MODE>
__global__ __launch_bounds__(1024) void capsF(
    const float* __restrict__ spart, float* __restrict__ vsumT,
    float* __restrict__ out) {
  __shared__ float sred[Dn][64];
  __shared__ float ssc[64];
  const int t = threadIdx.x, bl = t & 63, d = t >> 6;
  const int j = blockIdx.x, b = blockIdx.y * 64 + bl;

  const size_t cstride = (size_t)Jn * Dn * Bn;  // chunk stride in floats
  const float* sp = spart + ((size_t)j * Dn + d) * Bn + b;
  float s0 = 0.f, s1 = 0.f;
  #pragma unroll 4
  for (int ch = 0; ch < NCH; ch += 2) {
    s0 += sp[0];
    s1 += sp[cstride];
    sp += 2 * cstride;
  }
  const float s = s0 + s1;
  sred[d][bl] = s;
  __syncthreads();
  if (t < 64) {
    float n2 = 0.f;
    #pragma unroll
    for (int dd = 0; dd < Dn; ++dd) {
      const float z = sred[dd][bl];
      n2 = fmaf(z, z, n2);
    }
    ssc[bl] = n2 / (1.f + n2) / sqrtf(n2 + 1e-7f);
  }
  __syncthreads();
  const float v = s * ssc[bl];
  if (MODE == 2) {
    out[((size_t)b * Jn + j) * Dn + d] = v;
  } else if (MODE == 1) {
    vsumT[((size_t)j * Dn + d) * Bn + b] += v;
  } else {
    vsumT[((size_t)j * Dn + d) * Bn + b] = v;
  }
}

extern "C" void kernel_launch(void* const* d_in, const int* in_sizes, int n_in,
                              void* d_out, int out_size, void* d_ws, size_t ws_size,
                              hipStream_t stream) {
  const float* x = (const float*)d_in[0];  // [256,1152,8]
  const float* w = (const float*)d_in[1];  // [1152,10,16,8]
  float* xT    = (float*)d_ws;                      // [I*P][B]   9.44 MB
  float* vsumT = xT + (size_t)In * Pn * Bn;         // [J][D][B]  0.16 MB
  float* spart = vsumT + (size_t)Jn * Dn * Bn;      // [NCH][J][D][B] 15.73 MB
  float* out = (float*)d_out;                       // [256,10,16]

  xpose<<<dim3((In * Pn) / 64, Bn / 64), 256, 0, stream>>>(x, xT);

  capsA0<<<dim3(NCH, Jn), 256, 0, stream>>>(xT, w, spart);
  capsF<0><<<dim3(Jn, 4), 1024, 0, stream>>>(spart, vsumT, out);   // vsum = v0

  capsR<<<dim3(NCH, 4), 1024, 0, stream>>>(xT, w, vsumT, spart);   // round 1
  capsF<1><<<dim3(Jn, 4), 1024, 0, stream>>>(spart, vsumT, out);   // vsum += v1

  capsR<<<dim3(NCH, 4), 1024, 0, stream>>>(xT, w, vsumT, spart);   // round 2
  capsF<2><<<dim3(Jn, 4), 1024, 0, stream>>>(spart, vsumT, out);   // out = v2
}